// Round 1
// baseline (582.327 us; speedup 1.0000x reference)
//
#include <hip/hip_runtime.h>

typedef __attribute__((ext_vector_type(8))) short bfrag;   // 8 x bf16
typedef __attribute__((ext_vector_type(4))) float f4;

#define MFMA(a,b,c) __builtin_amdgcn_mfma_f32_16x16x32_bf16(a,b,c,0,0,0)

__device__ __forceinline__ unsigned short f2b(float x){
  union { float f; unsigned int u; } v; v.f = x;
  unsigned int r = v.u + 0x7fffu + ((v.u >> 16) & 1u);
  return (unsigned short)(r >> 16);
}

// ---------------- prep kernels ----------------
__global__ void k_trans(const float* __restrict__ W, unsigned short* __restrict__ Bt, int K, int N){
  int idx = blockIdx.x*256 + threadIdx.x;
  if (idx >= K*N) return;
  int k = idx / N, n = idx - k*N;
  Bt[(size_t)n*K + k] = f2b(W[idx]);
}

__global__ void k_attnred(const float* __restrict__ W, const float* __restrict__ attn,
                          const float* __restrict__ bvec, int K,
                          unsigned short* __restrict__ Bt, float* __restrict__ biasv){
  int idx = blockIdx.x*256 + threadIdx.x;   // over 4*K
  if (idx < 4*K) {
    int h = idx / K, k = idx - h*K;
    float s = 0.f;
    for (int d = 0; d < 128; ++d) s += W[(size_t)k*512 + h*128 + d] * attn[h*128 + d];
    Bt[(size_t)h*K + k] = f2b(s);
  }
  if (idx < 4) {
    float s = 0.f;
    for (int d = 0; d < 128; ++d) s += bvec[idx*128 + d] * attn[idx*128 + d];
    biasv[idx] = s;
  }
}

__global__ void k_copyf(const float* __restrict__ s, float* __restrict__ d, int n){
  int i = blockIdx.x*256 + threadIdx.x; if (i < n) d[i] = s[i];
}

__global__ void k_wsum(const float* __restrict__ qkv_w, float* __restrict__ wsum){
  int n = blockIdx.x*256 + threadIdx.x; if (n >= 1152) return;
  float s = 0.f;
  for (int k = 0; k < 128; ++k) s += qkv_w[(size_t)k*1152 + n];
  wsum[n] = s;
}

__global__ void k_gather(const float* __restrict__ embed, const int* __restrict__ ids,
                         float* __restrict__ Ei){
  int i = blockIdx.x*256 + threadIdx.x;      // N*256 exactly
  int n = i >> 8, c = i & 255;
  Ei[i] = embed[(size_t)ids[n]*256 + c];
}

__global__ void k_outcopy(const float* __restrict__ embed, const int* __restrict__ ids,
                          float* __restrict__ out){
  int i = blockIdx.x*256 + threadIdx.x;
  if (i < 12800000) out[1048576 + i] = embed[i];
  if (i < 8192)     out[13848576 + i] = (float)ids[i];
}

// ---------------- GEMM: C[M,N] = A[M,K](f32)@Bt[N,K](bf16)^T + bias ----------------
// mode 0: write C (ldc). mode 1: QKV pack + rank-1 (x*wsum) epilogue.
__global__ __launch_bounds__(256) void k_gemm(
    const float* __restrict__ A, int lda,
    const unsigned short* __restrict__ Bt, int K,
    const float* __restrict__ bias,
    float* __restrict__ C, int ldc, int mode,
    const float* __restrict__ xv, const float* __restrict__ wsum,
    unsigned short* __restrict__ qO, unsigned short* __restrict__ kO,
    unsigned short* __restrict__ vO)
{
  __shared__ unsigned short As[128*40];
  __shared__ unsigned short Bs[128*40];
  const int t = threadIdx.x;
  const int wid = t >> 6, l = t & 63;
  const int lr = l & 15, lg = l >> 4;
  const int arow0 = blockIdx.y*128, bn0 = blockIdx.x*128;
  const int wr = (wid >> 1)*64, wc = (wid & 1)*64;
  f4 zero = {0.f,0.f,0.f,0.f};
  f4 acc[4][4];
  #pragma unroll
  for (int i=0;i<4;++i)
    #pragma unroll
    for (int j=0;j<4;++j) acc[i][j] = zero;

  for (int k0 = 0; k0 < K; k0 += 32) {
    #pragma unroll
    for (int p=0;p<4;++p) {
      int row = p*32 + (t>>3);
      int c4  = (t&7)*4;
      float4 v = *reinterpret_cast<const float4*>(A + (size_t)(arow0+row)*lda + k0 + c4);
      ushort4 h4;
      h4.x = f2b(v.x); h4.y = f2b(v.y); h4.z = f2b(v.z); h4.w = f2b(v.w);
      *reinterpret_cast<ushort4*>(&As[row*40 + c4]) = h4;
    }
    #pragma unroll
    for (int p=0;p<2;++p) {
      int n  = p*64 + (t>>2);
      int c8 = (t&3)*8;
      int4 v = *reinterpret_cast<const int4*>(Bt + (size_t)(bn0+n)*K + k0 + c8);
      *reinterpret_cast<int4*>(&Bs[n*40 + c8]) = v;
    }
    __syncthreads();
    bfrag af[4], bfm[4];
    #pragma unroll
    for (int mi=0;mi<4;++mi) af[mi] = *reinterpret_cast<const bfrag*>(&As[(wr+mi*16+lr)*40 + lg*8]);
    #pragma unroll
    for (int ni=0;ni<4;++ni) bfm[ni] = *reinterpret_cast<const bfrag*>(&Bs[(wc+ni*16+lr)*40 + lg*8]);
    #pragma unroll
    for (int mi=0;mi<4;++mi)
      #pragma unroll
      for (int ni=0;ni<4;++ni)
        acc[mi][ni] = MFMA(af[mi], bfm[ni], acc[mi][ni]);
    __syncthreads();
  }
  #pragma unroll
  for (int mi=0;mi<4;++mi) {
    #pragma unroll
    for (int ni=0;ni<4;++ni) {
      int col = bn0 + wc + ni*16 + lr;
      float bv = bias[col];
      float wsv = (mode==1) ? wsum[col] : 0.f;
      #pragma unroll
      for (int i=0;i<4;++i) {
        int row = arow0 + wr + mi*16 + lg*4 + i;
        float val = acc[mi][ni][i] + bv;
        if (mode == 1) {
          val += xv[row]*wsv;
          unsigned short hv = f2b(val);
          if (col < 384)      qO[(size_t)row*384 + col] = hv;
          else if (col < 768) kO[(size_t)row*384 + col - 384] = hv;
          else                vO[(size_t)(col-768)*8192 + row] = hv;
        } else {
          C[(size_t)row*ldc + col] = val;
        }
      }
    }
  }
}

// ---------------- flash attention: QB=64, KB=32, KSPLIT=4 ----------------
__global__ __launch_bounds__(256,2) void k_flash(
    const unsigned short* __restrict__ qg,
    const unsigned short* __restrict__ kg,
    const unsigned short* __restrict__ vg,
    float* __restrict__ Opart, float* __restrict__ mpart, float* __restrict__ lpart)
{
  __shared__ unsigned short Ks[32*392];
  __shared__ unsigned short Vs[384*40];
  __shared__ float Ss[64*36];
  __shared__ unsigned short Ps[64*40];
  __shared__ float m_s[64], l_s[64], f_s[64];

  const int t = threadIdx.x;
  const int w = t >> 6, l = t & 63;
  const int lr = l & 15, lg = l >> 4;
  const int qbi = blockIdx.x >> 2, split = blockIdx.x & 3;
  const int qbase = qbi * 64;
  const float scale = 0.05103103631f;   // 384^-0.5

  bfrag qf[12];
  #pragma unroll
  for (int kk=0;kk<12;++kk)
    qf[kk] = *reinterpret_cast<const bfrag*>(qg + (size_t)(qbase + w*16 + lr)*384 + kk*32 + lg*8);

  f4 zero = {0.f,0.f,0.f,0.f};
  f4 o[4][6];
  #pragma unroll
  for (int a=0;a<4;++a)
    #pragma unroll
    for (int b=0;b<6;++b) o[a][b] = zero;

  if (t < 64) { m_s[t] = -3e38f; l_s[t] = 0.f; }
  __syncthreads();

  const int jend = split*2048 + 2048;
  for (int j0 = split*2048; j0 < jend; j0 += 32) {
    #pragma unroll
    for (int p=0;p<6;++p) {
      int idx = p*256 + t;
      int row = idx / 48, g = idx - row*48;
      int4 v = *reinterpret_cast<const int4*>(kg + (size_t)(j0+row)*384 + g*8);
      *reinterpret_cast<int4*>(&Ks[row*392 + g*8]) = v;
    }
    #pragma unroll
    for (int p=0;p<6;++p) {
      int idx = p*256 + t;
      int row = idx >> 2, g = idx & 3;
      int4 v = *reinterpret_cast<const int4*>(vg + (size_t)row*8192 + j0 + g*8);
      *reinterpret_cast<int4*>(&Vs[row*40 + g*8]) = v;
    }
    __syncthreads();
    f4 s0 = zero, s1 = zero;
    #pragma unroll
    for (int kk=0;kk<12;++kk) {
      bfrag b0 = *reinterpret_cast<const bfrag*>(&Ks[lr*392 + kk*32 + lg*8]);
      bfrag b1 = *reinterpret_cast<const bfrag*>(&Ks[(16+lr)*392 + kk*32 + lg*8]);
      s0 = MFMA(qf[kk], b0, s0);
      s1 = MFMA(qf[kk], b1, s1);
    }
    #pragma unroll
    for (int i=0;i<4;++i) {
      Ss[(w*16 + lg*4 + i)*36 + lr]      = s0[i];
      Ss[(w*16 + lg*4 + i)*36 + 16 + lr] = s1[i];
    }
    __syncthreads();
    {
      int row = t >> 2, cg = (t & 3) * 8;
      float4 sa = *reinterpret_cast<const float4*>(&Ss[row*36 + cg]);
      float4 sb = *reinterpret_cast<const float4*>(&Ss[row*36 + cg + 4]);
      float sv[8] = {sa.x,sa.y,sa.z,sa.w,sb.x,sb.y,sb.z,sb.w};
      float mt = -3e38f;
      #pragma unroll
      for (int i=0;i<8;++i){ sv[i] *= scale; mt = fmaxf(mt, sv[i]); }
      mt = fmaxf(mt, __shfl_xor(mt,1));
      mt = fmaxf(mt, __shfl_xor(mt,2));
      float mo = m_s[row];
      float mn = fmaxf(mo, mt);
      float sum = 0.f;
      unsigned int pk[4];
      #pragma unroll
      for (int i=0;i<4;++i) {
        float p0 = __expf(sv[2*i]-mn), p1 = __expf(sv[2*i+1]-mn);
        sum += p0 + p1;
        pk[i] = (unsigned int)f2b(p0) | ((unsigned int)f2b(p1) << 16);
      }
      sum += __shfl_xor(sum,1);
      sum += __shfl_xor(sum,2);
      *reinterpret_cast<int4*>(&Ps[row*40 + cg]) =
          make_int4((int)pk[0],(int)pk[1],(int)pk[2],(int)pk[3]);
      if ((t&3)==0) {
        float f = __expf(mo-mn);
        m_s[row] = mn; f_s[row] = f; l_s[row] = l_s[row]*f + sum;
      }
    }
    __syncthreads();
    #pragma unroll
    for (int omi=0; omi<4; ++omi) {
      #pragma unroll
      for (int i=0;i<4;++i) {
        float f = f_s[omi*16 + lg*4 + i];
        #pragma unroll
        for (int nj=0;nj<6;++nj) o[omi][nj][i] *= f;
      }
    }
    bfrag pa[4];
    #pragma unroll
    for (int omi=0;omi<4;++omi)
      pa[omi] = *reinterpret_cast<const bfrag*>(&Ps[(omi*16+lr)*40 + lg*8]);
    #pragma unroll
    for (int nj=0;nj<6;++nj) {
      bfrag vbf = *reinterpret_cast<const bfrag*>(&Vs[(w*96 + nj*16 + lr)*40 + lg*8]);
      #pragma unroll
      for (int omi=0;omi<4;++omi)
        o[omi][nj] = MFMA(pa[omi], vbf, o[omi][nj]);
    }
    __syncthreads();
  }
  float* Op = Opart + (size_t)split*8192*384;
  #pragma unroll
  for (int omi=0;omi<4;++omi)
    #pragma unroll
    for (int nj=0;nj<6;++nj)
      #pragma unroll
      for (int i=0;i<4;++i)
        Op[(size_t)(qbase + omi*16 + lg*4 + i)*384 + w*96 + nj*16 + lr] = o[omi][nj][i];
  if (t < 64) {
    mpart[split*8192 + qbase + t] = m_s[t];
    lpart[split*8192 + qbase + t] = l_s[t];
  }
}

__global__ void k_combine(const float* __restrict__ Op, const float* __restrict__ mp,
                          const float* __restrict__ lp, float* __restrict__ att)
{
  int gid = blockIdx.x*256 + threadIdx.x;   // 8192*384 exactly
  int row = gid / 384;
  float m0 = mp[row], m1 = mp[8192+row], m2 = mp[16384+row], m3 = mp[24576+row];
  float M = fmaxf(fmaxf(m0,m1), fmaxf(m2,m3));
  float w0 = __expf(m0-M), w1 = __expf(m1-M), w2 = __expf(m2-M), w3 = __expf(m3-M);
  float L = lp[row]*w0 + lp[8192+row]*w1 + lp[16384+row]*w2 + lp[24576+row]*w3;
  const size_t Z = (size_t)8192*384;
  float acc = Op[gid]*w0 + Op[Z+gid]*w1 + Op[2*Z+gid]*w2 + Op[3*Z+gid]*w3;
  att[gid] = acc / L;
}

// ---------------- LN1 + SiLU + residual ----------------
__global__ __launch_bounds__(256) void k_ln1(const float* __restrict__ pre, const float* __restrict__ Ei,
                      const float* __restrict__ g, const float* __restrict__ b,
                      float* __restrict__ out)
{
  int row = blockIdx.x, c = threadIdx.x;
  float v = pre[(size_t)row*256 + c];
  float s1 = v, s2 = v*v;
  #pragma unroll
  for (int o1=32;o1;o1>>=1){ s1 += __shfl_down(s1,o1); s2 += __shfl_down(s2,o1); }
  __shared__ float a1[4], a2[4];
  if ((c&63)==0){ a1[c>>6] = s1; a2[c>>6] = s2; }
  __syncthreads();
  float S1 = a1[0]+a1[1]+a1[2]+a1[3], S2 = a2[0]+a2[1]+a2[2]+a2[3];
  float mean = S1*(1.f/256.f), var = S2*(1.f/256.f) - mean*mean;
  float y = (v-mean)*rsqrtf(var+1e-5f)*g[c] + b[c];
  float sig = 1.f/(1.f+__expf(-y));
  out[(size_t)row*256 + c] = y*sig + Ei[(size_t)row*256 + c];
}

// ---------------- edge kernels ----------------
__global__ void k_escore(const int* __restrict__ ei, const float* __restrict__ ea,
                         const float* __restrict__ TC, int ldc, int aoff,
                         float* __restrict__ sc)
{
  int e = blockIdx.x*256 + threadIdx.x; if (e >= 131072) return;
  int s = ei[e], d = ei[131072 + e];
  float wv = ea[e];
  #pragma unroll
  for (int h=0; h<4; ++h) {
    float ai = TC[(size_t)d*ldc + aoff + h];
    float aj = TC[(size_t)s*ldc + aoff + 4 + h];
    sc[e*4 + h] = (ai + aj) * wv;
  }
}

__global__ __launch_bounds__(1024) void k_cstats(const float* __restrict__ sc,
                        float* __restrict__ mx, float* __restrict__ sm)
{
  int ch = blockIdx.x;                  // 16 = 4 chunks x 4 heads
  int c = ch >> 2, h = ch & 3;
  int t = threadIdx.x;
  const float* base = sc + (size_t)c*131072 + h;
  float m = -3e38f;
  for (int i=t; i<32768; i+=1024) m = fmaxf(m, base[(size_t)i*4]);
  #pragma unroll
  for (int o1=32;o1;o1>>=1) m = fmaxf(m, __shfl_down(m,o1));
  __shared__ float red[16];
  if ((t&63)==0) red[t>>6] = m;
  __syncthreads();
  if (t == 0) { float x = red[0]; for (int i=1;i<16;++i) x = fmaxf(x, red[i]); red[0] = x; }
  __syncthreads();
  float M = red[0];
  float s = 0.f;
  for (int i=t; i<32768; i+=1024) s += __expf(base[(size_t)i*4] - M);
  #pragma unroll
  for (int o1=32;o1;o1>>=1) s += __shfl_down(s,o1);
  __shared__ float red2[16];
  if ((t&63)==0) red2[t>>6] = s;
  __syncthreads();
  if (t == 0) { float x = 0.f; for (int i=0;i<16;++i) x += red2[i]; mx[ch] = M; sm[ch] = x; }
}

__global__ __launch_bounds__(256) void k_scatter(const int* __restrict__ ei, const float* __restrict__ sc,
                        const float* __restrict__ mx, const float* __restrict__ sm,
                        const float* __restrict__ TC, int ldc, float* __restrict__ g)
{
  int e = blockIdx.x*2 + (threadIdx.x >> 7);
  int d = threadIdx.x & 127;
  int s = ei[e], dst = ei[131072 + e];
  int ch = (e >> 15) * 4;
  float msg = 0.f;
  #pragma unroll
  for (int h=0; h<4; ++h) {
    float p = __expf(sc[e*4+h] - mx[ch+h]) / sm[ch+h];
    msg += TC[(size_t)s*ldc + h*128 + d] * p;
  }
  atomicAdd(&g[(size_t)dst*128 + d], msg);
}

// ---------------- final: skip1 GEMV + combine + LN2 ----------------
__global__ __launch_bounds__(128) void k_final(const float* __restrict__ g1, const float* __restrict__ TC1,
                       const float* __restrict__ sw, const float* __restrict__ sb,
                       const float* __restrict__ lg2, const float* __restrict__ lb2,
                       float* __restrict__ out)
{
  int row = blockIdx.x, c = threadIdx.x;
  __shared__ float gr[128];
  float gv = g1[(size_t)row*128 + c];
  gr[c] = gv; __syncthreads();
  float s1 = sb[c];
  #pragma unroll 8
  for (int k=0;k<128;++k) s1 += gr[k]*sw[k*128 + c];
  float s0 = TC1[(size_t)row*768 + 512 + c];
  float v = gv + 0.5f*(s0 + s1);
  float m1 = v, m2 = v*v;
  #pragma unroll
  for (int o1=32;o1;o1>>=1){ m1 += __shfl_down(m1,o1); m2 += __shfl_down(m2,o1); }
  __shared__ float a1[2], a2[2];
  if ((c&63)==0){ a1[c>>6]=m1; a2[c>>6]=m2; }
  __syncthreads();
  float S1 = a1[0]+a1[1], S2 = a2[0]+a2[1];
  float mean = S1*(1.f/128.f), var = S2*(1.f/128.f) - mean*mean;
  out[(size_t)row*128 + c] = (v-mean)*rsqrtf(var+1e-5f)*lg2[c] + lb2[c];
}

// ---------------- host launch ----------------
extern "C" void kernel_launch(void* const* d_in, const int* in_sizes, int n_in,
                              void* d_out, int out_size, void* d_ws, size_t ws_size,
                              hipStream_t stream)
{
  const int*   ids    = (const int*)  d_in[0];
  const float* x      = (const float*)d_in[1];
  const float* ea     = (const float*)d_in[2];
  const int*   eidx   = (const int*)  d_in[3];
  const float* embed  = (const float*)d_in[4];
  const float* qkv_w  = (const float*)d_in[5];
  const float* qkv_b  = (const float*)d_in[6];
  const float* proj_w = (const float*)d_in[7];
  const float* proj_b = (const float*)d_in[8];
  const float* fuse_w = (const float*)d_in[9];
  const float* fuse_b = (const float*)d_in[10];
  const float* ln1_g  = (const float*)d_in[11];
  const float* ln1_b  = (const float*)d_in[12];
  const float* wi0 = (const float*)d_in[13]; const float* bi0 = (const float*)d_in[14];
  const float* wj0 = (const float*)d_in[15]; const float* bj0 = (const float*)d_in[16];
  const float* wt0 = (const float*)d_in[17]; const float* bt0 = (const float*)d_in[18];
  const float* attn0 = (const float*)d_in[19];
  const float* sk0w = (const float*)d_in[20]; const float* sk0b = (const float*)d_in[21];
  const float* wi1 = (const float*)d_in[22]; const float* bi1 = (const float*)d_in[23];
  const float* wj1 = (const float*)d_in[24]; const float* bj1 = (const float*)d_in[25];
  const float* wt1 = (const float*)d_in[26]; const float* bt1 = (const float*)d_in[27];
  const float* attn1 = (const float*)d_in[28];
  const float* sk1w = (const float*)d_in[29]; const float* sk1b = (const float*)d_in[30];
  const float* ln2_g = (const float*)d_in[31]; const float* ln2_b = (const float*)d_in[32];

  char* ws = (char*)d_ws;
  const size_t MBy = (size_t)1 << 20;

  unsigned short* BtQKV  = (unsigned short*)(ws + 0);
  unsigned short* BtPROJ = (unsigned short*)(ws + 589824);
  unsigned short* BtFUSE = (unsigned short*)(ws + 884736);
  unsigned short* BtT0   = (unsigned short*)(ws + 1081344);
  unsigned short* BtT1   = (unsigned short*)(ws + 1409024);
  float* biasT0 = (float*)(ws + 1605632);
  float* biasT1 = (float*)(ws + 1608192);
  float* wsum   = (float*)(ws + 1611264);
  float* mxb    = (float*)(ws + 1615872);
  float* smb    = (float*)(ws + 1615936);

  float* Ei   = (float*)(ws + 2*MBy);
  unsigned short* qb = (unsigned short*)(ws + 10*MBy);
  unsigned short* kb = (unsigned short*)(ws + 17*MBy);
  unsigned short* vb = (unsigned short*)(ws + 24*MBy);
  float* att  = (float*)(ws + 31*MBy);
  float* z2   = (float*)(ws + 10*MBy);   // over qb/kb (dead after flash)
  float* pre  = (float*)(ws + 22*MBy);   // over kb tail/vt (dead)
  float* emb0 = (float*)(ws + 31*MBy);   // over att (dead after proj GEMM)
  float* TC0  = (float*)(ws + 39*MBy);
  float* sc0  = (float*)(ws + 59*MBy);
  float* g0   = (float*)(ws + 61*MBy);
  float* TC1  = (float*)(ws + 10*MBy);   // over z2/att (dead)
  float* sc1  = (float*)(ws + 34*MBy);
  float* g1   = (float*)(ws + 36*MBy);

  float* out = (float*)d_out;
  float* Opart = out;                    // d_out used as scratch, overwritten later
  float* mpart = out + 12582912;
  float* lpart = out + 12582912 + 32768;

  hipMemsetAsync(ws, 0, 2*MBy, stream);

  k_trans<<<(256*1152+255)/256, 256, 0, stream>>>(qkv_w + 128*1152, BtQKV, 256, 1152);
  k_trans<<<(384*384+255)/256, 256, 0, stream>>>(proj_w, BtPROJ, 384, 384);
  k_trans<<<(384*256+255)/256, 256, 0, stream>>>(fuse_w, BtFUSE, 384, 256);
  k_trans<<<(256*512+255)/256, 256, 0, stream>>>(wt0, BtT0, 256, 512);
  k_trans<<<(128*512+255)/256, 256, 0, stream>>>(wt1, BtT1, 128, 512);
  k_trans<<<(128*128+255)/256, 256, 0, stream>>>(sk0w, BtT1 + 512*128, 128, 128);
  k_attnred<<<4, 256, 0, stream>>>(wi0, attn0, bi0, 256, BtT0 + 512*256, biasT0 + 512);
  k_attnred<<<4, 256, 0, stream>>>(wj0, attn0, bj0, 256, BtT0 + 516*256, biasT0 + 516);
  k_attnred<<<2, 256, 0, stream>>>(wi1, attn1, bi1, 128, BtT1 + 640*128, biasT1 + 640);
  k_attnred<<<2, 256, 0, stream>>>(wj1, attn1, bj1, 128, BtT1 + 644*128, biasT1 + 644);
  k_copyf<<<2, 256, 0, stream>>>(bt0, biasT0, 512);
  k_copyf<<<2, 256, 0, stream>>>(bt1, biasT1, 512);
  k_copyf<<<1, 256, 0, stream>>>(sk0b, biasT1 + 512, 128);
  k_wsum<<<5, 256, 0, stream>>>(qkv_w, wsum);
  k_gather<<<8192, 256, 0, stream>>>(embed, ids, Ei);

  // QKV GEMM with rank-1 x term, packing q/k bf16 + v transposed bf16
  k_gemm<<<dim3(9,64), 256, 0, stream>>>(Ei, 256, BtQKV, 256, qkv_b, nullptr, 0, 1,
                                         x, wsum, qb, kb, vb);
  k_flash<<<512, 256, 0, stream>>>(qb, kb, vb, Opart, mpart, lpart);
  k_combine<<<12288, 256, 0, stream>>>(Opart, mpart, lpart, att);
  k_outcopy<<<50000, 256, 0, stream>>>(embed, ids, out);

  k_gemm<<<dim3(3,64), 256, 0, stream>>>(att, 384, BtPROJ, 384, proj_b, z2, 384, 0,
                                         nullptr, nullptr, nullptr, nullptr, nullptr);
  k_gemm<<<dim3(2,64), 256, 0, stream>>>(z2, 384, BtFUSE, 384, fuse_b, pre, 256, 0,
                                         nullptr, nullptr, nullptr, nullptr, nullptr);
  k_ln1<<<8192, 256, 0, stream>>>(pre, Ei, ln1_g, ln1_b, emb0);

  k_gemm<<<dim3(5,64), 256, 0, stream>>>(emb0, 256, BtT0, 256, biasT0, TC0, 640, 0,
                                         nullptr, nullptr, nullptr, nullptr, nullptr);
  k_escore<<<512, 256, 0, stream>>>(eidx, ea, TC0, 640, 512, sc0);
  k_cstats<<<16, 1024, 0, stream>>>(sc0, mxb, smb);
  hipMemsetAsync(g0, 0, (size_t)8192*128*4, stream);
  k_scatter<<<65536, 256, 0, stream>>>(eidx, sc0, mxb, smb, TC0, 640, g0);

  k_gemm<<<dim3(6,64), 256, 0, stream>>>(g0, 128, BtT1, 128, biasT1, TC1, 768, 0,
                                         nullptr, nullptr, nullptr, nullptr, nullptr);
  k_escore<<<512, 256, 0, stream>>>(eidx, ea, TC1, 768, 640, sc1);
  k_cstats<<<16, 1024, 0, stream>>>(sc1, mxb, smb);
  hipMemsetAsync(g1, 0, (size_t)8192*128*4, stream);
  k_scatter<<<65536, 256, 0, stream>>>(eidx, sc1, mxb, smb, TC1, 768, g1);

  k_final<<<8192, 128, 0, stream>>>(g1, TC1, sk1w, sk1b, ln2_g, ln2_b, out);
}

// Round 2
// 558.961 us; speedup vs baseline: 1.0418x; 1.0418x over previous
//
#include <hip/hip_runtime.h>

typedef __attribute__((ext_vector_type(8))) short bfrag;   // 8 x bf16
typedef __attribute__((ext_vector_type(4))) float f4;

#define MFMA(a,b,c) __builtin_amdgcn_mfma_f32_16x16x32_bf16(a,b,c,0,0,0)

__device__ __forceinline__ unsigned short f2b(float x){
  union { float f; unsigned int u; } v; v.f = x;
  unsigned int r = v.u + 0x7fffu + ((v.u >> 16) & 1u);
  return (unsigned short)(r >> 16);
}
__device__ __forceinline__ float b2f(unsigned short h){
  union { unsigned int u; float f; } v; v.u = ((unsigned int)h) << 16;
  return v.f;
}

// ---------------- prep kernels ----------------
__global__ void k_trans(const float* __restrict__ W, unsigned short* __restrict__ Bt, int K, int N){
  int idx = blockIdx.x*256 + threadIdx.x;
  if (idx >= K*N) return;
  int k = idx / N, n = idx - k*N;
  Bt[(size_t)n*K + k] = f2b(W[idx]);
}

__global__ void k_attnred(const float* __restrict__ W, const float* __restrict__ attn,
                          const float* __restrict__ bvec, int K,
                          unsigned short* __restrict__ Bt, float* __restrict__ biasv){
  int idx = blockIdx.x*256 + threadIdx.x;   // over 4*K
  if (idx < 4*K) {
    int h = idx / K, k = idx - h*K;
    float s = 0.f;
    for (int d = 0; d < 128; ++d) s += W[(size_t)k*512 + h*128 + d] * attn[h*128 + d];
    Bt[(size_t)h*K + k] = f2b(s);
  }
  if (idx < 4) {
    float s = 0.f;
    for (int d = 0; d < 128; ++d) s += bvec[idx*128 + d] * attn[idx*128 + d];
    biasv[idx] = s;
  }
}

__global__ void k_copyf(const float* __restrict__ s, float* __restrict__ d, int n){
  int i = blockIdx.x*256 + threadIdx.x; if (i < n) d[i] = s[i];
}

__global__ void k_wsum(const float* __restrict__ qkv_w, float* __restrict__ wsum){
  int n = blockIdx.x*256 + threadIdx.x; if (n >= 1152) return;
  float s = 0.f;
  for (int k = 0; k < 128; ++k) s += qkv_w[(size_t)k*1152 + n];
  wsum[n] = s;
}

__global__ void k_gather(const float* __restrict__ embed, const int* __restrict__ ids,
                         float* __restrict__ Ei){
  int i = blockIdx.x*256 + threadIdx.x;      // N*256 exactly
  int n = i >> 8, c = i & 255;
  Ei[i] = embed[(size_t)ids[n]*256 + c];
}

__global__ void k_outcopy(const float* __restrict__ embed, const int* __restrict__ ids,
                          float* __restrict__ out){
  int i = blockIdx.x*256 + threadIdx.x;
  if (i < 12800000) out[1048576 + i] = embed[i];
  if (i < 8192)     out[13848576 + i] = (float)ids[i];
}

// ---------------- CSR build ----------------
__global__ void k_deg(const int* __restrict__ ei, int* __restrict__ deg){
  int e = blockIdx.x*256 + threadIdx.x; if (e >= 131072) return;
  atomicAdd(&deg[ei[131072 + e]], 1);
}

__global__ __launch_bounds__(1024) void k_scan(const int* __restrict__ deg,
                                               int* __restrict__ off, int* __restrict__ cursor){
  int t = threadIdx.x;
  int v[8]; int s = 0;
  #pragma unroll
  for (int i=0;i<8;++i){ v[i] = s; s += deg[t*8 + i]; }
  int lane = t & 63, w = t >> 6;
  int si = s;
  for (int o=1;o<64;o<<=1){ int u = __shfl_up(si, o); if (lane >= o) si += u; }
  __shared__ int wsum[16];
  if (lane == 63) wsum[w] = si;
  __syncthreads();
  if (t < 16) {
    int x = wsum[t];
    for (int o=1;o<16;o<<=1){ int u = __shfl_up(x, o); if (t >= o) x += u; }
    wsum[t] = x;
  }
  __syncthreads();
  int wbase = (w == 0) ? 0 : wsum[w-1];
  int base = wbase + (si - s);
  #pragma unroll
  for (int i=0;i<8;++i){ int o2 = base + v[i]; off[t*8+i] = o2; cursor[t*8+i] = o2; }
  if (t == 1023) off[8192] = wbase + si;
}

__global__ void k_fill(const int* __restrict__ ei, int* __restrict__ cursor,
                       int* __restrict__ elist){
  int e = blockIdx.x*256 + threadIdx.x; if (e >= 131072) return;
  int d = ei[131072 + e];
  int slot = atomicAdd(&cursor[d], 1);
  elist[slot] = e;
}

// ---------------- GEMM: C[M,N] = A[M,K](f32)@Bt[N,K](bf16)^T + bias ----------------
__global__ __launch_bounds__(256) void k_gemm(
    const float* __restrict__ A, int lda,
    const unsigned short* __restrict__ Bt, int K,
    const float* __restrict__ bias,
    float* __restrict__ C, int ldc, int mode,
    const float* __restrict__ xv, const float* __restrict__ wsum,
    unsigned short* __restrict__ qO, unsigned short* __restrict__ kO,
    unsigned short* __restrict__ vO)
{
  __shared__ unsigned short As[128*40];
  __shared__ unsigned short Bs[128*40];
  const int t = threadIdx.x;
  const int wid = t >> 6, l = t & 63;
  const int lr = l & 15, lg = l >> 4;
  const int arow0 = blockIdx.y*128, bn0 = blockIdx.x*128;
  const int wr = (wid >> 1)*64, wc = (wid & 1)*64;
  f4 zero = {0.f,0.f,0.f,0.f};
  f4 acc[4][4];
  #pragma unroll
  for (int i=0;i<4;++i)
    #pragma unroll
    for (int j=0;j<4;++j) acc[i][j] = zero;

  for (int k0 = 0; k0 < K; k0 += 32) {
    #pragma unroll
    for (int p=0;p<4;++p) {
      int row = p*32 + (t>>3);
      int c4  = (t&7)*4;
      float4 v = *reinterpret_cast<const float4*>(A + (size_t)(arow0+row)*lda + k0 + c4);
      ushort4 h4;
      h4.x = f2b(v.x); h4.y = f2b(v.y); h4.z = f2b(v.z); h4.w = f2b(v.w);
      *reinterpret_cast<ushort4*>(&As[row*40 + c4]) = h4;
    }
    #pragma unroll
    for (int p=0;p<2;++p) {
      int n  = p*64 + (t>>2);
      int c8 = (t&3)*8;
      int4 v = *reinterpret_cast<const int4*>(Bt + (size_t)(bn0+n)*K + k0 + c8);
      *reinterpret_cast<int4*>(&Bs[n*40 + c8]) = v;
    }
    __syncthreads();
    bfrag af[4], bfm[4];
    #pragma unroll
    for (int mi=0;mi<4;++mi) af[mi] = *reinterpret_cast<const bfrag*>(&As[(wr+mi*16+lr)*40 + lg*8]);
    #pragma unroll
    for (int ni=0;ni<4;++ni) bfm[ni] = *reinterpret_cast<const bfrag*>(&Bs[(wc+ni*16+lr)*40 + lg*8]);
    #pragma unroll
    for (int mi=0;mi<4;++mi)
      #pragma unroll
      for (int ni=0;ni<4;++ni)
        acc[mi][ni] = MFMA(af[mi], bfm[ni], acc[mi][ni]);
    __syncthreads();
  }
  #pragma unroll
  for (int mi=0;mi<4;++mi) {
    #pragma unroll
    for (int ni=0;ni<4;++ni) {
      int col = bn0 + wc + ni*16 + lr;
      float bv = bias[col];
      float wsv = (mode==1) ? wsum[col] : 0.f;
      #pragma unroll
      for (int i=0;i<4;++i) {
        int row = arow0 + wr + mi*16 + lg*4 + i;
        float val = acc[mi][ni][i] + bv;
        if (mode == 1) {
          val += xv[row]*wsv;
          unsigned short hv = f2b(val);
          if (col < 384)      qO[(size_t)row*384 + col] = hv;
          else if (col < 768) kO[(size_t)row*384 + col - 384] = hv;
          else                vO[(size_t)(col-768)*8192 + row] = hv;
        } else {
          C[(size_t)row*ldc + col] = val;
        }
      }
    }
  }
}

// ---------------- flash attention: QB=64, KB=32, KSPLIT=4, bf16 partials ----------------
__global__ __launch_bounds__(256,2) void k_flash(
    const unsigned short* __restrict__ qg,
    const unsigned short* __restrict__ kg,
    const unsigned short* __restrict__ vg,
    unsigned short* __restrict__ Opart, float* __restrict__ mpart, float* __restrict__ lpart)
{
  __shared__ unsigned short Ks[32*392];
  __shared__ unsigned short Vs[384*40];
  __shared__ float Ss[64*36];
  __shared__ unsigned short Ps[64*40];
  __shared__ float m_s[64], l_s[64], f_s[64];

  const int t = threadIdx.x;
  const int w = t >> 6, l = t & 63;
  const int lr = l & 15, lg = l >> 4;
  const int qbi = blockIdx.x >> 2, split = blockIdx.x & 3;
  const int qbase = qbi * 64;
  const float scale = 0.05103103631f;   // 384^-0.5

  bfrag qf[12];
  #pragma unroll
  for (int kk=0;kk<12;++kk)
    qf[kk] = *reinterpret_cast<const bfrag*>(qg + (size_t)(qbase + w*16 + lr)*384 + kk*32 + lg*8);

  f4 zero = {0.f,0.f,0.f,0.f};
  f4 o[4][6];
  #pragma unroll
  for (int a=0;a<4;++a)
    #pragma unroll
    for (int b=0;b<6;++b) o[a][b] = zero;

  if (t < 64) { m_s[t] = -3e38f; l_s[t] = 0.f; }
  __syncthreads();

  const int jend = split*2048 + 2048;
  for (int j0 = split*2048; j0 < jend; j0 += 32) {
    #pragma unroll
    for (int p=0;p<6;++p) {
      int idx = p*256 + t;
      int row = idx / 48, g = idx - row*48;
      int4 v = *reinterpret_cast<const int4*>(kg + (size_t)(j0+row)*384 + g*8);
      *reinterpret_cast<int4*>(&Ks[row*392 + g*8]) = v;
    }
    #pragma unroll
    for (int p=0;p<6;++p) {
      int idx = p*256 + t;
      int row = idx >> 2, g = idx & 3;
      int4 v = *reinterpret_cast<const int4*>(vg + (size_t)row*8192 + j0 + g*8);
      *reinterpret_cast<int4*>(&Vs[row*40 + g*8]) = v;
    }
    __syncthreads();
    f4 s0 = zero, s1 = zero;
    #pragma unroll
    for (int kk=0;kk<12;++kk) {
      bfrag b0 = *reinterpret_cast<const bfrag*>(&Ks[lr*392 + kk*32 + lg*8]);
      bfrag b1 = *reinterpret_cast<const bfrag*>(&Ks[(16+lr)*392 + kk*32 + lg*8]);
      s0 = MFMA(qf[kk], b0, s0);
      s1 = MFMA(qf[kk], b1, s1);
    }
    #pragma unroll
    for (int i=0;i<4;++i) {
      Ss[(w*16 + lg*4 + i)*36 + lr]      = s0[i];
      Ss[(w*16 + lg*4 + i)*36 + 16 + lr] = s1[i];
    }
    __syncthreads();
    {
      int row = t >> 2, cg = (t & 3) * 8;
      float4 sa = *reinterpret_cast<const float4*>(&Ss[row*36 + cg]);
      float4 sb = *reinterpret_cast<const float4*>(&Ss[row*36 + cg + 4]);
      float sv[8] = {sa.x,sa.y,sa.z,sa.w,sb.x,sb.y,sb.z,sb.w};
      float mt = -3e38f;
      #pragma unroll
      for (int i=0;i<8;++i){ sv[i] *= scale; mt = fmaxf(mt, sv[i]); }
      mt = fmaxf(mt, __shfl_xor(mt,1));
      mt = fmaxf(mt, __shfl_xor(mt,2));
      float mo = m_s[row];
      float mn = fmaxf(mo, mt);
      float sum = 0.f;
      unsigned int pk[4];
      #pragma unroll
      for (int i=0;i<4;++i) {
        float p0 = __expf(sv[2*i]-mn), p1 = __expf(sv[2*i+1]-mn);
        sum += p0 + p1;
        pk[i] = (unsigned int)f2b(p0) | ((unsigned int)f2b(p1) << 16);
      }
      sum += __shfl_xor(sum,1);
      sum += __shfl_xor(sum,2);
      *reinterpret_cast<int4*>(&Ps[row*40 + cg]) =
          make_int4((int)pk[0],(int)pk[1],(int)pk[2],(int)pk[3]);
      if ((t&3)==0) {
        float f = __expf(mo-mn);
        m_s[row] = mn; f_s[row] = f; l_s[row] = l_s[row]*f + sum;
      }
    }
    __syncthreads();
    #pragma unroll
    for (int omi=0; omi<4; ++omi) {
      #pragma unroll
      for (int i=0;i<4;++i) {
        float f = f_s[omi*16 + lg*4 + i];
        #pragma unroll
        for (int nj=0;nj<6;++nj) o[omi][nj][i] *= f;
      }
    }
    bfrag pa[4];
    #pragma unroll
    for (int omi=0;omi<4;++omi)
      pa[omi] = *reinterpret_cast<const bfrag*>(&Ps[(omi*16+lr)*40 + lg*8]);
    #pragma unroll
    for (int nj=0;nj<6;++nj) {
      bfrag vbf = *reinterpret_cast<const bfrag*>(&Vs[(w*96 + nj*16 + lr)*40 + lg*8]);
      #pragma unroll
      for (int omi=0;omi<4;++omi)
        o[omi][nj] = MFMA(pa[omi], vbf, o[omi][nj]);
    }
    __syncthreads();
  }
  unsigned short* Op = Opart + (size_t)split*8192*384;
  #pragma unroll
  for (int omi=0;omi<4;++omi)
    #pragma unroll
    for (int nj=0;nj<6;++nj)
      #pragma unroll
      for (int i=0;i<4;++i)
        Op[(size_t)(qbase + omi*16 + lg*4 + i)*384 + w*96 + nj*16 + lr] = f2b(o[omi][nj][i]);
  if (t < 64) {
    mpart[split*8192 + qbase + t] = m_s[t];
    lpart[split*8192 + qbase + t] = l_s[t];
  }
}

__global__ void k_combine(const unsigned short* __restrict__ Op, const float* __restrict__ mp,
                          const float* __restrict__ lp, float* __restrict__ att)
{
  int gid = blockIdx.x*256 + threadIdx.x;   // 8192*384 exactly
  int row = gid / 384;
  float m0 = mp[row], m1 = mp[8192+row], m2 = mp[16384+row], m3 = mp[24576+row];
  float M = fmaxf(fmaxf(m0,m1), fmaxf(m2,m3));
  float w0 = __expf(m0-M), w1 = __expf(m1-M), w2 = __expf(m2-M), w3 = __expf(m3-M);
  float L = lp[row]*w0 + lp[8192+row]*w1 + lp[16384+row]*w2 + lp[24576+row]*w3;
  const size_t Z = (size_t)8192*384;
  float acc = b2f(Op[gid])*w0 + b2f(Op[Z+gid])*w1 + b2f(Op[2*Z+gid])*w2 + b2f(Op[3*Z+gid])*w3;
  att[gid] = acc / L;
}

// ---------------- LN1 + SiLU + residual ----------------
__global__ __launch_bounds__(256) void k_ln1(const float* __restrict__ pre, const float* __restrict__ Ei,
                      const float* __restrict__ g, const float* __restrict__ b,
                      float* __restrict__ out)
{
  int row = blockIdx.x, c = threadIdx.x;
  float v = pre[(size_t)row*256 + c];
  float s1 = v, s2 = v*v;
  #pragma unroll
  for (int o1=32;o1;o1>>=1){ s1 += __shfl_down(s1,o1); s2 += __shfl_down(s2,o1); }
  __shared__ float a1[4], a2[4];
  if ((c&63)==0){ a1[c>>6] = s1; a2[c>>6] = s2; }
  __syncthreads();
  float S1 = a1[0]+a1[1]+a1[2]+a1[3], S2 = a2[0]+a2[1]+a2[2]+a2[3];
  float mean = S1*(1.f/256.f), var = S2*(1.f/256.f) - mean*mean;
  float y = (v-mean)*rsqrtf(var+1e-5f)*g[c] + b[c];
  float sig = 1.f/(1.f+__expf(-y));
  out[(size_t)row*256 + c] = y*sig + Ei[(size_t)row*256 + c];
}

// ---------------- edge kernels ----------------
__global__ void k_escore(const int* __restrict__ ei, const float* __restrict__ ea,
                         const float* __restrict__ TC, int ldc, int aoff,
                         float* __restrict__ sc)
{
  int e = blockIdx.x*256 + threadIdx.x; if (e >= 131072) return;
  int s = ei[e], d = ei[131072 + e];
  float wv = ea[e];
  #pragma unroll
  for (int h=0; h<4; ++h) {
    float ai = TC[(size_t)d*ldc + aoff + h];
    float aj = TC[(size_t)s*ldc + aoff + 4 + h];
    sc[e*4 + h] = (ai + aj) * wv;
  }
}

__global__ __launch_bounds__(1024) void k_cstats(const float* __restrict__ sc,
                        float* __restrict__ mx, float* __restrict__ sm)
{
  int ch = blockIdx.x;                  // 16 = 4 chunks x 4 heads
  int c = ch >> 2, h = ch & 3;
  int t = threadIdx.x;
  const float* base = sc + (size_t)c*131072 + h;
  float m = -3e38f;
  for (int i=t; i<32768; i+=1024) m = fmaxf(m, base[(size_t)i*4]);
  #pragma unroll
  for (int o1=32;o1;o1>>=1) m = fmaxf(m, __shfl_down(m,o1));
  __shared__ float red[16];
  if ((t&63)==0) red[t>>6] = m;
  __syncthreads();
  if (t == 0) { float x = red[0]; for (int i=1;i<16;++i) x = fmaxf(x, red[i]); red[0] = x; }
  __syncthreads();
  float M = red[0];
  float s = 0.f;
  for (int i=t; i<32768; i+=1024) s += __expf(base[(size_t)i*4] - M);
  #pragma unroll
  for (int o1=32;o1;o1>>=1) s += __shfl_down(s,o1);
  __shared__ float red2[16];
  if ((t&63)==0) red2[t>>6] = s;
  __syncthreads();
  if (t == 0) { float x = 0.f; for (int i=0;i<16;++i) x += red2[i]; mx[ch] = M; sm[ch] = x; }
}

__global__ void k_pnorm(float* __restrict__ sc, const float* __restrict__ mx,
                        const float* __restrict__ sm)
{
  int i = blockIdx.x*256 + threadIdx.x;   // 524288 exactly
  int e = i >> 2, h = i & 3;
  int ch = (e >> 15)*4 + h;
  sc[i] = __expf(sc[i] - mx[ch]) / sm[ch];
}

// CSR gather-aggregate: one block (128 threads) per destination node
__global__ __launch_bounds__(128) void k_aggr(const int* __restrict__ off,
                      const int* __restrict__ elist, const int* __restrict__ ei,
                      const float* __restrict__ sc,
                      const float* __restrict__ TC, int ldc, float* __restrict__ g)
{
  int n = blockIdx.x, d = threadIdx.x;
  int qb = off[n], qe = off[n+1];
  float acc = 0.f;
  for (int q = qb; q < qe; ++q) {
    int e = elist[q];
    int s = ei[e];
    float4 p = *reinterpret_cast<const float4*>(&sc[e*4]);
    const float* Tr = TC + (size_t)s*ldc;
    acc += p.x*Tr[d] + p.y*Tr[128+d] + p.z*Tr[256+d] + p.w*Tr[384+d];
  }
  g[(size_t)n*128 + d] = acc;
}

// ---------------- final: skip1 GEMV + combine + LN2 ----------------
__global__ __launch_bounds__(128) void k_final(const float* __restrict__ g1, const float* __restrict__ TC1,
                       const float* __restrict__ sw, const float* __restrict__ sb,
                       const float* __restrict__ lg2, const float* __restrict__ lb2,
                       float* __restrict__ out)
{
  int row = blockIdx.x, c = threadIdx.x;
  __shared__ float gr[128];
  float gv = g1[(size_t)row*128 + c];
  gr[c] = gv; __syncthreads();
  float s1 = sb[c];
  #pragma unroll 8
  for (int k=0;k<128;++k) s1 += gr[k]*sw[k*128 + c];
  float s0 = TC1[(size_t)row*768 + 512 + c];
  float v = gv + 0.5f*(s0 + s1);
  float m1 = v, m2 = v*v;
  #pragma unroll
  for (int o1=32;o1;o1>>=1){ m1 += __shfl_down(m1,o1); m2 += __shfl_down(m2,o1); }
  __shared__ float a1[2], a2[2];
  if ((c&63)==0){ a1[c>>6]=m1; a2[c>>6]=m2; }
  __syncthreads();
  float S1 = a1[0]+a1[1], S2 = a2[0]+a2[1];
  float mean = S1*(1.f/128.f), var = S2*(1.f/128.f) - mean*mean;
  out[(size_t)row*128 + c] = (v-mean)*rsqrtf(var+1e-5f)*lg2[c] + lb2[c];
}

// ---------------- host launch ----------------
extern "C" void kernel_launch(void* const* d_in, const int* in_sizes, int n_in,
                              void* d_out, int out_size, void* d_ws, size_t ws_size,
                              hipStream_t stream)
{
  const int*   ids    = (const int*)  d_in[0];
  const float* x      = (const float*)d_in[1];
  const float* ea     = (const float*)d_in[2];
  const int*   eidx   = (const int*)  d_in[3];
  const float* embed  = (const float*)d_in[4];
  const float* qkv_w  = (const float*)d_in[5];
  const float* qkv_b  = (const float*)d_in[6];
  const float* proj_w = (const float*)d_in[7];
  const float* proj_b = (const float*)d_in[8];
  const float* fuse_w = (const float*)d_in[9];
  const float* fuse_b = (const float*)d_in[10];
  const float* ln1_g  = (const float*)d_in[11];
  const float* ln1_b  = (const float*)d_in[12];
  const float* wi0 = (const float*)d_in[13]; const float* bi0 = (const float*)d_in[14];
  const float* wj0 = (const float*)d_in[15]; const float* bj0 = (const float*)d_in[16];
  const float* wt0 = (const float*)d_in[17]; const float* bt0 = (const float*)d_in[18];
  const float* attn0 = (const float*)d_in[19];
  const float* sk0w = (const float*)d_in[20]; const float* sk0b = (const float*)d_in[21];
  const float* wi1 = (const float*)d_in[22]; const float* bi1 = (const float*)d_in[23];
  const float* wj1 = (const float*)d_in[24]; const float* bj1 = (const float*)d_in[25];
  const float* wt1 = (const float*)d_in[26]; const float* bt1 = (const float*)d_in[27];
  const float* attn1 = (const float*)d_in[28];
  const float* sk1w = (const float*)d_in[29]; const float* sk1b = (const float*)d_in[30];
  const float* ln2_g = (const float*)d_in[31]; const float* ln2_b = (const float*)d_in[32];

  char* ws = (char*)d_ws;
  const size_t MBy = (size_t)1 << 20;

  // static area (0..2MB), zeroed each call
  unsigned short* BtQKV  = (unsigned short*)(ws + 0);
  unsigned short* BtPROJ = (unsigned short*)(ws + 589824);
  unsigned short* BtFUSE = (unsigned short*)(ws + 884736);
  unsigned short* BtT0   = (unsigned short*)(ws + 1081344);
  unsigned short* BtT1   = (unsigned short*)(ws + 1409024);
  float* biasT0 = (float*)(ws + 1605632);
  float* biasT1 = (float*)(ws + 1608192);
  float* wsum   = (float*)(ws + 1611264);
  float* mxb    = (float*)(ws + 1615872);
  float* smb    = (float*)(ws + 1615936);
  int* deg    = (int*)(ws + 1703936);
  int* cursor = (int*)(ws + 1736704);
  int* off    = (int*)(ws + 1769472);

  float* Ei   = (float*)(ws + 2*MBy);               // 2..10 MB
  unsigned short* qb = (unsigned short*)(ws + 10*MBy);  // 10..16.3
  unsigned short* kb = (unsigned short*)(ws + 17*MBy);  // 17..23.3
  unsigned short* vb = (unsigned short*)(ws + 24*MBy);  // 24..30.3
  float* att  = (float*)(ws + 31*MBy);              // 31..43.6
  float* z2   = (float*)(ws + 10*MBy);              // over qb/kb (dead)
  float* pre  = (float*)(ws + 45*MBy);              // 45..53.4 (TC0 not yet written)
  float* emb0 = (float*)(ws + 31*MBy);              // over att (dead)
  float* TC0  = (float*)(ws + 43*MBy);              // 43..64 (exactly 21MB)
  float* sc0  = (float*)(ws + 26*MBy);              // 26..28.1 (pre? no: kb/vb dead zone)
  float* g0   = (float*)(ws + 2*MBy);               // over Ei (dead after ln1)
  float* TC1  = (float*)(ws + 6*MBy);               // 6..31.2 (qb/kb/vb/z2/sc0 dead)
  float* sc1  = (float*)(ws + 43*MBy);              // 43..45 (TC0 dead)
  float* g1   = (float*)(ws + 47448064);            // 45.25..49.25
  int* elist  = (int*)(ws + 64*MBy);                // 64..64.5

  float* out = (float*)d_out;
  unsigned short* Opart = (unsigned short*)d_out;   // bf16 partials, overwritten later
  float* mpart = out + 6815744;                     // 26MB offset
  float* lpart = out + 6848512;

  hipMemsetAsync(ws, 0, 2*MBy, stream);

  // CSR build (independent of everything else)
  k_deg<<<512, 256, 0, stream>>>(eidx, deg);
  k_scan<<<1, 1024, 0, stream>>>(deg, off, cursor);
  k_fill<<<512, 256, 0, stream>>>(eidx, cursor, elist);

  k_trans<<<(256*1152+255)/256, 256, 0, stream>>>(qkv_w + 128*1152, BtQKV, 256, 1152);
  k_trans<<<(384*384+255)/256, 256, 0, stream>>>(proj_w, BtPROJ, 384, 384);
  k_trans<<<(384*256+255)/256, 256, 0, stream>>>(fuse_w, BtFUSE, 384, 256);
  k_trans<<<(256*512+255)/256, 256, 0, stream>>>(wt0, BtT0, 256, 512);
  k_trans<<<(128*512+255)/256, 256, 0, stream>>>(wt1, BtT1, 128, 512);
  k_trans<<<(128*128+255)/256, 256, 0, stream>>>(sk0w, BtT1 + 512*128, 128, 128);
  k_attnred<<<4, 256, 0, stream>>>(wi0, attn0, bi0, 256, BtT0 + 512*256, biasT0 + 512);
  k_attnred<<<4, 256, 0, stream>>>(wj0, attn0, bj0, 256, BtT0 + 516*256, biasT0 + 516);
  k_attnred<<<2, 256, 0, stream>>>(wi1, attn1, bi1, 128, BtT1 + 640*128, biasT1 + 640);
  k_attnred<<<2, 256, 0, stream>>>(wj1, attn1, bj1, 128, BtT1 + 644*128, biasT1 + 644);
  k_copyf<<<2, 256, 0, stream>>>(bt0, biasT0, 512);
  k_copyf<<<2, 256, 0, stream>>>(bt1, biasT1, 512);
  k_copyf<<<1, 256, 0, stream>>>(sk0b, biasT1 + 512, 128);
  k_wsum<<<5, 256, 0, stream>>>(qkv_w, wsum);
  k_gather<<<8192, 256, 0, stream>>>(embed, ids, Ei);

  // QKV GEMM with rank-1 x term, packing q/k bf16 + v transposed bf16
  k_gemm<<<dim3(9,64), 256, 0, stream>>>(Ei, 256, BtQKV, 256, qkv_b, nullptr, 0, 1,
                                         x, wsum, qb, kb, vb);
  k_flash<<<512, 256, 0, stream>>>(qb, kb, vb, Opart, mpart, lpart);
  k_combine<<<12288, 256, 0, stream>>>(Opart, mpart, lpart, att);
  k_outcopy<<<50000, 256, 0, stream>>>(embed, ids, out);

  k_gemm<<<dim3(3,64), 256, 0, stream>>>(att, 384, BtPROJ, 384, proj_b, z2, 384, 0,
                                         nullptr, nullptr, nullptr, nullptr, nullptr);
  k_gemm<<<dim3(2,64), 256, 0, stream>>>(z2, 384, BtFUSE, 384, fuse_b, pre, 256, 0,
                                         nullptr, nullptr, nullptr, nullptr, nullptr);
  k_ln1<<<8192, 256, 0, stream>>>(pre, Ei, ln1_g, ln1_b, emb0);

  // WGAT layer 0
  k_gemm<<<dim3(5,64), 256, 0, stream>>>(emb0, 256, BtT0, 256, biasT0, TC0, 640, 0,
                                         nullptr, nullptr, nullptr, nullptr, nullptr);
  k_escore<<<512, 256, 0, stream>>>(eidx, ea, TC0, 640, 512, sc0);
  k_cstats<<<16, 1024, 0, stream>>>(sc0, mxb, smb);
  k_pnorm<<<2048, 256, 0, stream>>>(sc0, mxb, smb);
  k_aggr<<<8192, 128, 0, stream>>>(off, elist, eidx, sc0, TC0, 640, g0);

  // WGAT layer 1
  k_gemm<<<dim3(6,64), 256, 0, stream>>>(g0, 128, BtT1, 128, biasT1, TC1, 768, 0,
                                         nullptr, nullptr, nullptr, nullptr, nullptr);
  k_escore<<<512, 256, 0, stream>>>(eidx, ea, TC1, 768, 640, sc1);
  k_cstats<<<16, 1024, 0, stream>>>(sc1, mxb, smb);
  k_pnorm<<<2048, 256, 0, stream>>>(sc1, mxb, smb);
  k_aggr<<<8192, 128, 0, stream>>>(off, elist, eidx, sc1, TC1, 768, g1);

  k_final<<<8192, 128, 0, stream>>>(g1, TC1, sk1w, sk1b, ln2_g, ln2_b, out);
}

// Round 3
// 526.481 us; speedup vs baseline: 1.1061x; 1.0617x over previous
//
#include <hip/hip_runtime.h>

typedef __attribute__((ext_vector_type(8))) short bfrag;   // 8 x bf16
typedef __attribute__((ext_vector_type(4))) float f4;

#define MFMA(a,b,c) __builtin_amdgcn_mfma_f32_16x16x32_bf16(a,b,c,0,0,0)

__device__ __forceinline__ unsigned short f2b(float x){
  union { float f; unsigned int u; } v; v.f = x;
  unsigned int r = v.u + 0x7fffu + ((v.u >> 16) & 1u);
  return (unsigned short)(r >> 16);
}
__device__ __forceinline__ float b2f(unsigned short h){
  union { unsigned int u; float f; } v; v.u = ((unsigned int)h) << 16;
  return v.f;
}

// ---------------- merged prep kernel ----------------
__global__ __launch_bounds__(256) void k_prep(
    const float* __restrict__ qkv_w, const float* __restrict__ proj_w,
    const float* __restrict__ fuse_w, const float* __restrict__ wt0,
    const float* __restrict__ wt1, const float* __restrict__ sk0w,
    const float* __restrict__ wi0, const float* __restrict__ bi0,
    const float* __restrict__ wj0, const float* __restrict__ bj0,
    const float* __restrict__ wi1, const float* __restrict__ bi1,
    const float* __restrict__ wj1, const float* __restrict__ bj1,
    const float* __restrict__ attn0, const float* __restrict__ attn1,
    const float* __restrict__ bt0, const float* __restrict__ bt1,
    const float* __restrict__ sk0b,
    const float* __restrict__ embed, const int* __restrict__ ids,
    unsigned short* __restrict__ BtQKV, unsigned short* __restrict__ BtPROJ,
    unsigned short* __restrict__ BtFUSE, unsigned short* __restrict__ BtT0,
    unsigned short* __restrict__ BtT1,
    float* __restrict__ biasT0, float* __restrict__ biasT1,
    float* __restrict__ wsum, float* __restrict__ Ei)
{
  int b = blockIdx.x, t = threadIdx.x;
  if (b < 1152) {            // QKV weight rows 128..383, transpose to [1152][256]
    int idx = b*256 + t; int k = idx/1152, n = idx - k*1152;
    BtQKV[(size_t)n*256 + k] = f2b(qkv_w[128*1152 + idx]);
  } else if (b < 1728) {     // proj 384x384
    int idx = (b-1152)*256 + t; int k = idx/384, n = idx - k*384;
    BtPROJ[(size_t)n*384 + k] = f2b(proj_w[idx]);
  } else if (b < 2112) {     // fuse 384x256
    int idx = (b-1728)*256 + t; int k = idx/256, n = idx - k*256;
    BtFUSE[(size_t)n*384 + k] = f2b(fuse_w[idx]);
  } else if (b < 2624) {     // wt0 256x512
    int idx = (b-2112)*256 + t; int k = idx/512, n = idx - k*512;
    BtT0[(size_t)n*256 + k] = f2b(wt0[idx]);
  } else if (b < 2880) {     // wt1 128x512
    int idx = (b-2624)*256 + t; int k = idx/512, n = idx - k*512;
    BtT1[(size_t)n*128 + k] = f2b(wt1[idx]);
  } else if (b < 2944) {     // sk0w 128x128 -> after wt1 block
    int idx = (b-2880)*256 + t; int k = idx/128, n = idx - k*128;
    BtT1[(size_t)(512+n)*128 + k] = f2b(sk0w[idx]);
  } else if (b < 2948) {     // attnred wi0 (K=256)
    int idx = (b-2944)*256 + t;
    int h = idx >> 8, k = idx & 255;
    float s = 0.f;
    for (int d = 0; d < 128; ++d) s += wi0[(size_t)k*512 + h*128 + d] * attn0[h*128 + d];
    BtT0[(size_t)(512 + h)*256 + k] = f2b(s);
    if (idx < 4) {
      float sb = 0.f;
      for (int d = 0; d < 128; ++d) sb += bi0[idx*128 + d] * attn0[idx*128 + d];
      biasT0[512 + idx] = sb;
    }
  } else if (b < 2952) {     // attnred wj0
    int idx = (b-2948)*256 + t;
    int h = idx >> 8, k = idx & 255;
    float s = 0.f;
    for (int d = 0; d < 128; ++d) s += wj0[(size_t)k*512 + h*128 + d] * attn0[h*128 + d];
    BtT0[(size_t)(516 + h)*256 + k] = f2b(s);
    if (idx < 4) {
      float sb = 0.f;
      for (int d = 0; d < 128; ++d) sb += bj0[idx*128 + d] * attn0[idx*128 + d];
      biasT0[516 + idx] = sb;
    }
  } else if (b < 2954) {     // attnred wi1 (K=128)
    int idx = (b-2952)*256 + t;
    int h = idx >> 7, k = idx & 127;
    float s = 0.f;
    for (int d = 0; d < 128; ++d) s += wi1[(size_t)k*512 + h*128 + d] * attn1[h*128 + d];
    BtT1[(size_t)(640 + h)*128 + k] = f2b(s);
    if (idx < 4) {
      float sb = 0.f;
      for (int d = 0; d < 128; ++d) sb += bi1[idx*128 + d] * attn1[idx*128 + d];
      biasT1[640 + idx] = sb;
    }
  } else if (b < 2956) {     // attnred wj1
    int idx = (b-2954)*256 + t;
    int h = idx >> 7, k = idx & 127;
    float s = 0.f;
    for (int d = 0; d < 128; ++d) s += wj1[(size_t)k*512 + h*128 + d] * attn1[h*128 + d];
    BtT1[(size_t)(644 + h)*128 + k] = f2b(s);
    if (idx < 4) {
      float sb = 0.f;
      for (int d = 0; d < 128; ++d) sb += bj1[idx*128 + d] * attn1[idx*128 + d];
      biasT1[644 + idx] = sb;
    }
  } else if (b < 2958) {     // copy bt0
    int idx = (b-2956)*256 + t; biasT0[idx] = bt0[idx];
  } else if (b < 2960) {     // copy bt1
    int idx = (b-2958)*256 + t; biasT1[idx] = bt1[idx];
  } else if (b < 2961) {     // copy sk0b
    if (t < 128) biasT1[512 + t] = sk0b[t];
  } else if (b < 2966) {     // wsum
    int n = (b-2961)*256 + t;
    if (n < 1152) {
      float s = 0.f;
      for (int k = 0; k < 128; ++k) s += qkv_w[(size_t)k*1152 + n];
      wsum[n] = s;
    }
  } else {                   // gather Ei (float4): 524288 elems
    int idx = (b-2966)*256 + t;
    int n = idx >> 6, c4 = idx & 63;
    reinterpret_cast<float4*>(Ei)[idx] =
        reinterpret_cast<const float4*>(embed + (size_t)ids[n]*256)[c4];
  }
}

__global__ void k_outcopy(const float* __restrict__ embed, const int* __restrict__ ids,
                          float* __restrict__ out){
  int i = blockIdx.x*256 + threadIdx.x;
  if (i < 3200000)
    reinterpret_cast<float4*>(out)[262144 + i] = reinterpret_cast<const float4*>(embed)[i];
  if (i < 8192) out[13848576 + i] = (float)ids[i];
}

// ---------------- CSR build ----------------
__global__ void k_deg(const int* __restrict__ ei, int* __restrict__ deg){
  int e = blockIdx.x*256 + threadIdx.x; if (e >= 131072) return;
  atomicAdd(&deg[ei[131072 + e]], 1);
}

__global__ __launch_bounds__(1024) void k_scan(const int* __restrict__ deg,
                                               int* __restrict__ off, int* __restrict__ cursor){
  int t = threadIdx.x;
  int v[8]; int s = 0;
  #pragma unroll
  for (int i=0;i<8;++i){ v[i] = s; s += deg[t*8 + i]; }
  int lane = t & 63, w = t >> 6;
  int si = s;
  for (int o=1;o<64;o<<=1){ int u = __shfl_up(si, o); if (lane >= o) si += u; }
  __shared__ int wsum[16];
  if (lane == 63) wsum[w] = si;
  __syncthreads();
  if (t < 16) {
    int x = wsum[t];
    for (int o=1;o<16;o<<=1){ int u = __shfl_up(x, o); if (t >= o) x += u; }
    wsum[t] = x;
  }
  __syncthreads();
  int wbase = (w == 0) ? 0 : wsum[w-1];
  int base = wbase + (si - s);
  #pragma unroll
  for (int i=0;i<8;++i){ int o2 = base + v[i]; off[t*8+i] = o2; cursor[t*8+i] = o2; }
  if (t == 1023) off[8192] = wbase + si;
}

__global__ void k_fill(const int* __restrict__ ei, int* __restrict__ cursor,
                       int* __restrict__ elist){
  int e = blockIdx.x*256 + threadIdx.x; if (e >= 131072) return;
  int d = ei[131072 + e];
  int slot = atomicAdd(&cursor[d], 1);
  elist[slot] = e;
}

// ---------------- GEMM: C[M,N] = A[M,K](f32)@Bt[N,K](bf16)^T + bias ----------------
__global__ __launch_bounds__(256) void k_gemm(
    const float* __restrict__ A, int lda,
    const unsigned short* __restrict__ Bt, int K,
    const float* __restrict__ bias,
    float* __restrict__ C, int ldc, int mode,
    const float* __restrict__ xv, const float* __restrict__ wsum,
    unsigned short* __restrict__ qO, unsigned short* __restrict__ kO,
    unsigned short* __restrict__ vO)
{
  __shared__ unsigned short As[128*40];
  __shared__ unsigned short Bs[128*40];
  const int t = threadIdx.x;
  const int wid = t >> 6, l = t & 63;
  const int lr = l & 15, lg = l >> 4;
  const int arow0 = blockIdx.y*128, bn0 = blockIdx.x*128;
  const int wr = (wid >> 1)*64, wc = (wid & 1)*64;
  f4 zero = {0.f,0.f,0.f,0.f};
  f4 acc[4][4];
  #pragma unroll
  for (int i=0;i<4;++i)
    #pragma unroll
    for (int j=0;j<4;++j) acc[i][j] = zero;

  for (int k0 = 0; k0 < K; k0 += 32) {
    #pragma unroll
    for (int p=0;p<4;++p) {
      int row = p*32 + (t>>3);
      int c4  = (t&7)*4;
      float4 v = *reinterpret_cast<const float4*>(A + (size_t)(arow0+row)*lda + k0 + c4);
      ushort4 h4;
      h4.x = f2b(v.x); h4.y = f2b(v.y); h4.z = f2b(v.z); h4.w = f2b(v.w);
      *reinterpret_cast<ushort4*>(&As[row*40 + c4]) = h4;
    }
    #pragma unroll
    for (int p=0;p<2;++p) {
      int n  = p*64 + (t>>2);
      int c8 = (t&3)*8;
      int4 v = *reinterpret_cast<const int4*>(Bt + (size_t)(bn0+n)*K + k0 + c8);
      *reinterpret_cast<int4*>(&Bs[n*40 + c8]) = v;
    }
    __syncthreads();
    bfrag af[4], bfm[4];
    #pragma unroll
    for (int mi=0;mi<4;++mi) af[mi] = *reinterpret_cast<const bfrag*>(&As[(wr+mi*16+lr)*40 + lg*8]);
    #pragma unroll
    for (int ni=0;ni<4;++ni) bfm[ni] = *reinterpret_cast<const bfrag*>(&Bs[(wc+ni*16+lr)*40 + lg*8]);
    #pragma unroll
    for (int mi=0;mi<4;++mi)
      #pragma unroll
      for (int ni=0;ni<4;++ni)
        acc[mi][ni] = MFMA(af[mi], bfm[ni], acc[mi][ni]);
    __syncthreads();
  }
  #pragma unroll
  for (int mi=0;mi<4;++mi) {
    #pragma unroll
    for (int ni=0;ni<4;++ni) {
      int col = bn0 + wc + ni*16 + lr;
      float bv = bias[col];
      float wsv = (mode==1) ? wsum[col] : 0.f;
      #pragma unroll
      for (int i=0;i<4;++i) {
        int row = arow0 + wr + mi*16 + lg*4 + i;
        float val = acc[mi][ni][i] + bv;
        if (mode == 1) {
          val += xv[row]*wsv;
          if (col < 384) val *= 0.05103103631f;   // fold attention scale into Q
          unsigned short hv = f2b(val);
          if (col < 384)      qO[(size_t)row*384 + col] = hv;
          else if (col < 768) kO[(size_t)row*384 + col - 384] = hv;
          else                vO[(size_t)(col-768)*8192 + row] = hv;
        } else {
          C[(size_t)row*ldc + col] = val;
        }
      }
    }
  }
}

// ---------------- flash attention v2: 2 barriers/iter, K via global_load_lds,
//                  V direct-to-frag, in-register softmax ----------------
__global__ __launch_bounds__(256,2) void k_flash(
    const unsigned short* __restrict__ qg,
    const unsigned short* __restrict__ kg,
    const unsigned short* __restrict__ vg,
    unsigned short* __restrict__ Opart, float* __restrict__ mpart, float* __restrict__ lpart)
{
  __shared__ unsigned short Ks[32*384];   // XOR-swizzled 16B units
  __shared__ unsigned short Ps[64*40];
  __shared__ float m_s[64], l_s[64], f_s[64];

  const int t = threadIdx.x;
  const int w = t >> 6, l = t & 63;
  const int lr = l & 15, lg = l >> 4;
  const int qbi = blockIdx.x >> 2, split = blockIdx.x & 3;
  const int qbase = qbi * 64;

  // staging geometry: 32 rows x 48 units(16B); LDS linear, global pre-swizzled
  #define STAGE(JJ) do { \
    _Pragma("unroll") \
    for (int p_=0;p_<6;++p_) { \
      int idx_ = p_*256 + t; \
      int row_ = idx_ / 48, uu_ = idx_ - row_*48; \
      int ug_ = uu_ ^ (row_ & 7); \
      const unsigned short* gp_ = kg + (size_t)((JJ) + row_)*384 + ug_*8; \
      __builtin_amdgcn_global_load_lds((const __attribute__((address_space(1))) void*)gp_, \
          (__attribute__((address_space(3))) void*)&Ks[idx_*8], 16, 0, 0); \
    } } while(0)

  bfrag qf[12];
  #pragma unroll
  for (int kk=0;kk<12;++kk)
    qf[kk] = *reinterpret_cast<const bfrag*>(qg + (size_t)(qbase + w*16 + lr)*384 + kk*32 + lg*8);

  f4 zero = {0.f,0.f,0.f,0.f};
  f4 o[4][6];
  #pragma unroll
  for (int a=0;a<4;++a)
    #pragma unroll
    for (int b=0;b<6;++b) o[a][b] = zero;

  const int j0beg = split*2048, jend = j0beg + 2048;

  STAGE(j0beg);
  if (t < 64) { m_s[t] = -3e38f; l_s[t] = 0.f; }
  __syncthreads();   // drains vmcnt: K tile 0 ready

  for (int j0 = j0beg; j0 < jend; j0 += 32) {
    // A: V fragments straight from global (transposed layout [d][n])
    bfrag vf[6];
    #pragma unroll
    for (int nj=0;nj<6;++nj)
      vf[nj] = *reinterpret_cast<const bfrag*>(vg + (size_t)(w*96 + nj*16 + lr)*8192 + j0 + lg*8);

    // B: QK^T from swizzled Ks
    f4 s0 = zero, s1 = zero;
    __builtin_amdgcn_s_setprio(1);
    #pragma unroll
    for (int kk=0;kk<12;++kk) {
      int su = ((kk*4 + lg) ^ (lr & 7)) * 8;
      bfrag b0 = *reinterpret_cast<const bfrag*>(&Ks[lr*384 + su]);
      bfrag b1 = *reinterpret_cast<const bfrag*>(&Ks[(16+lr)*384 + su]);
      s0 = MFMA(qf[kk], b0, s0);
      s1 = MFMA(qf[kk], b1, s1);
    }
    __builtin_amdgcn_s_setprio(0);

    // C: in-register online softmax (rows w*16+lg*4+i; cols lr / 16+lr)
    #pragma unroll
    for (int i=0;i<4;++i) {
      int row = w*16 + lg*4 + i;
      float mt = fmaxf(s0[i], s1[i]);
      mt = fmaxf(mt, __shfl_xor(mt, 1));
      mt = fmaxf(mt, __shfl_xor(mt, 2));
      mt = fmaxf(mt, __shfl_xor(mt, 4));
      mt = fmaxf(mt, __shfl_xor(mt, 8));
      float mo = m_s[row];
      float mn = fmaxf(mo, mt);
      float p0 = __expf(s0[i] - mn), p1 = __expf(s1[i] - mn);
      float sum = p0 + p1;
      sum += __shfl_xor(sum, 1);
      sum += __shfl_xor(sum, 2);
      sum += __shfl_xor(sum, 4);
      sum += __shfl_xor(sum, 8);
      Ps[row*40 + lr]      = f2b(p0);
      Ps[row*40 + 16 + lr] = f2b(p1);
      if (lr == 0) {
        float f = __expf(mo - mn);
        m_s[row] = mn; f_s[row] = f; l_s[row] = l_s[row]*f + sum;
      }
    }
    __syncthreads();   // B1: Ps + f_s ready; Ks fully consumed

    // D: prefetch next K tile (lands before B2's implicit vmcnt drain)
    if (j0 + 32 < jend) STAGE(j0 + 32);

    // E: rescale + PV
    #pragma unroll
    for (int omi=0; omi<4; ++omi) {
      #pragma unroll
      for (int i=0;i<4;++i) {
        float f = f_s[omi*16 + lg*4 + i];
        #pragma unroll
        for (int nj=0;nj<6;++nj) o[omi][nj][i] *= f;
      }
    }
    bfrag pa[4];
    #pragma unroll
    for (int omi=0;omi<4;++omi)
      pa[omi] = *reinterpret_cast<const bfrag*>(&Ps[(omi*16+lr)*40 + lg*8]);
    __builtin_amdgcn_s_setprio(1);
    #pragma unroll
    for (int nj=0;nj<6;++nj)
      #pragma unroll
      for (int omi=0;omi<4;++omi)
        o[omi][nj] = MFMA(pa[omi], vf[nj], o[omi][nj]);
    __builtin_amdgcn_s_setprio(0);
    __syncthreads();   // B2: drains K prefetch; Ps consumed
  }
  #undef STAGE

  unsigned short* Op = Opart + (size_t)split*8192*384;
  #pragma unroll
  for (int omi=0;omi<4;++omi)
    #pragma unroll
    for (int nj=0;nj<6;++nj)
      #pragma unroll
      for (int i=0;i<4;++i)
        Op[(size_t)(qbase + omi*16 + lg*4 + i)*384 + w*96 + nj*16 + lr] = f2b(o[omi][nj][i]);
  if (t < 64) {
    mpart[split*8192 + qbase + t] = m_s[t];
    lpart[split*8192 + qbase + t] = l_s[t];
  }
}

__global__ void k_combine(const unsigned short* __restrict__ Op, const float* __restrict__ mp,
                          const float* __restrict__ lp, float* __restrict__ att)
{
  int gid = blockIdx.x*256 + threadIdx.x;   // 8192*384 exactly
  int row = gid / 384;
  float m0 = mp[row], m1 = mp[8192+row], m2 = mp[16384+row], m3 = mp[24576+row];
  float M = fmaxf(fmaxf(m0,m1), fmaxf(m2,m3));
  float w0 = __expf(m0-M), w1 = __expf(m1-M), w2 = __expf(m2-M), w3 = __expf(m3-M);
  float L = lp[row]*w0 + lp[8192+row]*w1 + lp[16384+row]*w2 + lp[24576+row]*w3;
  const size_t Z = (size_t)8192*384;
  float acc = b2f(Op[gid])*w0 + b2f(Op[Z+gid])*w1 + b2f(Op[2*Z+gid])*w2 + b2f(Op[3*Z+gid])*w3;
  att[gid] = acc / L;
}

// ---------------- LN1 + SiLU + residual ----------------
__global__ __launch_bounds__(256) void k_ln1(const float* __restrict__ pre, const float* __restrict__ Ei,
                      const float* __restrict__ g, const float* __restrict__ b,
                      float* __restrict__ out)
{
  int row = blockIdx.x, c = threadIdx.x;
  float v = pre[(size_t)row*256 + c];
  float s1 = v, s2 = v*v;
  #pragma unroll
  for (int o1=32;o1;o1>>=1){ s1 += __shfl_down(s1,o1); s2 += __shfl_down(s2,o1); }
  __shared__ float a1[4], a2[4];
  if ((c&63)==0){ a1[c>>6] = s1; a2[c>>6] = s2; }
  __syncthreads();
  float S1 = a1[0]+a1[1]+a1[2]+a1[3], S2 = a2[0]+a2[1]+a2[2]+a2[3];
  float mean = S1*(1.f/256.f), var = S2*(1.f/256.f) - mean*mean;
  float y = (v-mean)*rsqrtf(var+1e-5f)*g[c] + b[c];
  float sig = 1.f/(1.f+__expf(-y));
  out[(size_t)row*256 + c] = y*sig + Ei[(size_t)row*256 + c];
}

// ---------------- edge kernels ----------------
__global__ void k_escore(const int* __restrict__ ei, const float* __restrict__ ea,
                         const float* __restrict__ TC, int ldc, int aoff,
                         float* __restrict__ sc)
{
  int e = blockIdx.x*256 + threadIdx.x; if (e >= 131072) return;
  int s = ei[e], d = ei[131072 + e];
  float wv = ea[e];
  #pragma unroll
  for (int h=0; h<4; ++h) {
    float ai = TC[(size_t)d*ldc + aoff + h];
    float aj = TC[(size_t)s*ldc + aoff + 4 + h];
    sc[e*4 + h] = (ai + aj) * wv;
  }
}

__global__ __launch_bounds__(1024) void k_cstats(const float* __restrict__ sc,
                        float* __restrict__ mx, float* __restrict__ sm)
{
  int ch = blockIdx.x;                  // 16 = 4 chunks x 4 heads
  int c = ch >> 2, h = ch & 3;
  int t = threadIdx.x;
  const float* base = sc + (size_t)c*131072 + h;
  float m = -3e38f;
  for (int i=t; i<32768; i+=1024) m = fmaxf(m, base[(size_t)i*4]);
  #pragma unroll
  for (int o1=32;o1;o1>>=1) m = fmaxf(m, __shfl_down(m,o1));
  __shared__ float red[16];
  if ((t&63)==0) red[t>>6] = m;
  __syncthreads();
  if (t == 0) { float x = red[0]; for (int i=1;i<16;++i) x = fmaxf(x, red[i]); red[0] = x; }
  __syncthreads();
  float M = red[0];
  float s = 0.f;
  for (int i=t; i<32768; i+=1024) s += __expf(base[(size_t)i*4] - M);
  #pragma unroll
  for (int o1=32;o1;o1>>=1) s += __shfl_down(s,o1);
  __shared__ float red2[16];
  if ((t&63)==0) red2[t>>6] = s;
  __syncthreads();
  if (t == 0) { float x = 0.f; for (int i=0;i<16;++i) x += red2[i]; mx[ch] = M; sm[ch] = x; }
}

__global__ void k_pnorm(float* __restrict__ sc, const float* __restrict__ mx,
                        const float* __restrict__ sm)
{
  int i = blockIdx.x*256 + threadIdx.x;   // 524288 exactly
  int e = i >> 2, h = i & 3;
  int ch = (e >> 15)*4 + h;
  sc[i] = __expf(sc[i] - mx[ch]) / sm[ch];
}

// CSR gather-aggregate: one block (128 threads) per destination node
__global__ __launch_bounds__(128) void k_aggr(const int* __restrict__ off,
                      const int* __restrict__ elist, const int* __restrict__ ei,
                      const float* __restrict__ sc,
                      const float* __restrict__ TC, int ldc, float* __restrict__ g)
{
  int n = blockIdx.x, d = threadIdx.x;
  int qb = off[n], qe = off[n+1];
  float acc = 0.f;
  for (int q = qb; q < qe; ++q) {
    int e = elist[q];
    int s = ei[e];
    float4 p = *reinterpret_cast<const float4*>(&sc[e*4]);
    const float* Tr = TC + (size_t)s*ldc;
    acc += p.x*Tr[d] + p.y*Tr[128+d] + p.z*Tr[256+d] + p.w*Tr[384+d];
  }
  g[(size_t)n*128 + d] = acc;
}

// ---------------- final: skip1 GEMV + combine + LN2 ----------------
__global__ __launch_bounds__(128) void k_final(const float* __restrict__ g1, const float* __restrict__ TC1,
                       const float* __restrict__ sw, const float* __restrict__ sb,
                       const float* __restrict__ lg2, const float* __restrict__ lb2,
                       float* __restrict__ out)
{
  int row = blockIdx.x, c = threadIdx.x;
  __shared__ float gr[128];
  float gv = g1[(size_t)row*128 + c];
  gr[c] = gv; __syncthreads();
  float s1 = sb[c];
  #pragma unroll 8
  for (int k=0;k<128;++k) s1 += gr[k]*sw[k*128 + c];
  float s0 = TC1[(size_t)row*768 + 512 + c];
  float v = gv + 0.5f*(s0 + s1);
  float m1 = v, m2 = v*v;
  #pragma unroll
  for (int o1=32;o1;o1>>=1){ m1 += __shfl_down(m1,o1); m2 += __shfl_down(m2,o1); }
  __shared__ float a1[2], a2[2];
  if ((c&63)==0){ a1[c>>6]=m1; a2[c>>6]=m2; }
  __syncthreads();
  float S1 = a1[0]+a1[1], S2 = a2[0]+a2[1];
  float mean = S1*(1.f/128.f), var = S2*(1.f/128.f) - mean*mean;
  out[(size_t)row*128 + c] = (v-mean)*rsqrtf(var+1e-5f)*lg2[c] + lb2[c];
}

// ---------------- host launch ----------------
extern "C" void kernel_launch(void* const* d_in, const int* in_sizes, int n_in,
                              void* d_out, int out_size, void* d_ws, size_t ws_size,
                              hipStream_t stream)
{
  const int*   ids    = (const int*)  d_in[0];
  const float* x      = (const float*)d_in[1];
  const float* ea     = (const float*)d_in[2];
  const int*   eidx   = (const int*)  d_in[3];
  const float* embed  = (const float*)d_in[4];
  const float* qkv_w  = (const float*)d_in[5];
  const float* qkv_b  = (const float*)d_in[6];
  const float* proj_w = (const float*)d_in[7];
  const float* proj_b = (const float*)d_in[8];
  const float* fuse_w = (const float*)d_in[9];
  const float* fuse_b = (const float*)d_in[10];
  const float* ln1_g  = (const float*)d_in[11];
  const float* ln1_b  = (const float*)d_in[12];
  const float* wi0 = (const float*)d_in[13]; const float* bi0 = (const float*)d_in[14];
  const float* wj0 = (const float*)d_in[15]; const float* bj0 = (const float*)d_in[16];
  const float* wt0 = (const float*)d_in[17]; const float* bt0 = (const float*)d_in[18];
  const float* attn0 = (const float*)d_in[19];
  const float* sk0w = (const float*)d_in[20]; const float* sk0b = (const float*)d_in[21];
  const float* wi1 = (const float*)d_in[22]; const float* bi1 = (const float*)d_in[23];
  const float* wj1 = (const float*)d_in[24]; const float* bj1 = (const float*)d_in[25];
  const float* wt1 = (const float*)d_in[26]; const float* bt1 = (const float*)d_in[27];
  const float* attn1 = (const float*)d_in[28];
  const float* sk1w = (const float*)d_in[29]; const float* sk1b = (const float*)d_in[30];
  const float* ln2_g = (const float*)d_in[31]; const float* ln2_b = (const float*)d_in[32];

  char* ws = (char*)d_ws;
  const size_t MBy = (size_t)1 << 20;

  // static area (0..2MB), zeroed each call
  unsigned short* BtQKV  = (unsigned short*)(ws + 0);
  unsigned short* BtPROJ = (unsigned short*)(ws + 589824);
  unsigned short* BtFUSE = (unsigned short*)(ws + 884736);
  unsigned short* BtT0   = (unsigned short*)(ws + 1081344);
  unsigned short* BtT1   = (unsigned short*)(ws + 1409024);
  float* biasT0 = (float*)(ws + 1605632);
  float* biasT1 = (float*)(ws + 1608192);
  float* wsum   = (float*)(ws + 1611264);
  float* mxb    = (float*)(ws + 1615872);
  float* smb    = (float*)(ws + 1615936);
  int* deg    = (int*)(ws + 1703936);
  int* cursor = (int*)(ws + 1736704);
  int* off    = (int*)(ws + 1769472);

  float* Ei   = (float*)(ws + 2*MBy);               // 2..10 MB
  unsigned short* qb = (unsigned short*)(ws + 10*MBy);  // 10..16.3
  unsigned short* kb = (unsigned short*)(ws + 17*MBy);  // 17..23.3
  unsigned short* vb = (unsigned short*)(ws + 24*MBy);  // 24..30.3
  float* att  = (float*)(ws + 31*MBy);              // 31..43.6
  float* z2   = (float*)(ws + 10*MBy);              // over qb/kb (dead)
  float* pre  = (float*)(ws + 45*MBy);              // 45..53.4
  float* emb0 = (float*)(ws + 31*MBy);              // over att (dead)
  float* TC0  = (float*)(ws + 43*MBy);              // 43..64
  float* sc0  = (float*)(ws + 26*MBy);              // kb/vb dead zone
  float* g0   = (float*)(ws + 2*MBy);               // over Ei (dead after ln1)
  float* TC1  = (float*)(ws + 6*MBy);               // qb/kb/vb dead
  float* sc1  = (float*)(ws + 43*MBy);              // TC0 dead
  float* g1   = (float*)(ws + 47448064);
  int* elist  = (int*)(ws + 64*MBy);

  float* out = (float*)d_out;
  unsigned short* Opart = (unsigned short*)d_out;   // bf16 partials, overwritten later
  float* mpart = out + 6815744;
  float* lpart = out + 6848512;

  hipMemsetAsync(ws, 0, 2*MBy, stream);

  k_prep<<<5014, 256, 0, stream>>>(qkv_w, proj_w, fuse_w, wt0, wt1, sk0w,
                                   wi0, bi0, wj0, bj0, wi1, bi1, wj1, bj1,
                                   attn0, attn1, bt0, bt1, sk0b, embed, ids,
                                   BtQKV, BtPROJ, BtFUSE, BtT0, BtT1,
                                   biasT0, biasT1, wsum, Ei);
  k_deg<<<512, 256, 0, stream>>>(eidx, deg);
  k_scan<<<1, 1024, 0, stream>>>(deg, off, cursor);
  k_fill<<<512, 256, 0, stream>>>(eidx, cursor, elist);

  // QKV GEMM with rank-1 x term, packing q(scaled)/k bf16 + v transposed bf16
  k_gemm<<<dim3(9,64), 256, 0, stream>>>(Ei, 256, BtQKV, 256, qkv_b, nullptr, 0, 1,
                                         x, wsum, qb, kb, vb);
  k_flash<<<512, 256, 0, stream>>>(qb, kb, vb, Opart, mpart, lpart);
  k_combine<<<12288, 256, 0, stream>>>(Opart, mpart, lpart, att);
  k_outcopy<<<12500, 256, 0, stream>>>(embed, ids, out);

  k_gemm<<<dim3(3,64), 256, 0, stream>>>(att, 384, BtPROJ, 384, proj_b, z2, 384, 0,
                                         nullptr, nullptr, nullptr, nullptr, nullptr);
  k_gemm<<<dim3(2,64), 256, 0, stream>>>(z2, 384, BtFUSE, 384, fuse_b, pre, 256, 0,
                                         nullptr, nullptr, nullptr, nullptr, nullptr);
  k_ln1<<<8192, 256, 0, stream>>>(pre, Ei, ln1_g, ln1_b, emb0);

  // WGAT layer 0
  k_gemm<<<dim3(5,64), 256, 0, stream>>>(emb0, 256, BtT0, 256, biasT0, TC0, 640, 0,
                                         nullptr, nullptr, nullptr, nullptr, nullptr);
  k_escore<<<512, 256, 0, stream>>>(eidx, ea, TC0, 640, 512, sc0);
  k_cstats<<<16, 1024, 0, stream>>>(sc0, mxb, smb);
  k_pnorm<<<2048, 256, 0, stream>>>(sc0, mxb, smb);
  k_aggr<<<8192, 128, 0, stream>>>(off, elist, eidx, sc0, TC0, 640, g0);

  // WGAT layer 1
  k_gemm<<<dim3(6,64), 256, 0, stream>>>(g0, 128, BtT1, 128, biasT1, TC1, 768, 0,
                                         nullptr, nullptr, nullptr, nullptr, nullptr);
  k_escore<<<512, 256, 0, stream>>>(eidx, ea, TC1, 768, 640, sc1);
  k_cstats<<<16, 1024, 0, stream>>>(sc1, mxb, smb);
  k_pnorm<<<2048, 256, 0, stream>>>(sc1, mxb, smb);
  k_aggr<<<8192, 128, 0, stream>>>(off, elist, eidx, sc1, TC1, 768, g1);

  k_final<<<8192, 128, 0, stream>>>(g1, TC1, sk1w, sk1b, ln2_g, ln2_b, out);
}